// Round 16
// baseline (276.282 us; speedup 1.0000x reference)
//
#include <hip/hip_runtime.h>
#include <hip/hip_bf16.h>

#define RNUM 8
#define HH1 32
#define HH2 16
#define FIN 128
#define BNODES 256      // nodes per bucket
#define NBMAX 512
#define PCHUNK 8192     // edges per partition block
#define SORTCAP 11264   // max PADDED edges per bucket the LDS sort handles

#define W1STR 136       // padded col stride (shorts) for Wcat  [288][136]
#define W1ELTS (288 * W1STR)
#define W2STR 40        // padded col stride (shorts) for W2cat [144][40]
#define W2ELTS (144 * W2STR)

typedef short bf16x8 __attribute__((ext_vector_type(8)));
typedef float f32x4 __attribute__((ext_vector_type(4)));

__device__ inline bf16x8 cvt8r(float4 a, float4 b) {
  float tmp[8] = {a.x, a.y, a.z, a.w, b.x, b.y, b.z, b.w};
  bf16x8 r;
  #pragma unroll
  for (int j = 0; j < 8; ++j) {
    union { __hip_bfloat16 h; short s; } cv;
    cv.h = __float2bfloat16(tmp[j]);
    r[j] = cv.s;
  }
  return r;
}

__device__ inline bf16x8 cvt8relu(const float* __restrict__ p) {
  float tmp[8];
  *(float4*)tmp = *(const float4*)p;
  *(float4*)(tmp + 4) = *(const float4*)(p + 4);
  bf16x8 r;
  #pragma unroll
  for (int j = 0; j < 8; ++j) {
    union { __hip_bfloat16 h; short s; } cv;
    cv.h = __float2bfloat16(fmaxf(tmp[j], 0.f));
    r[j] = cv.s;
  }
  return r;
}

__device__ inline uint2 pack4bf(f32x4 v) {
  union { unsigned short u[4]; uint2 w; } pk;
  union { __hip_bfloat16 h; unsigned short s; } cv;
  cv.h = __float2bfloat16(v[0]); pk.u[0] = cv.s;
  cv.h = __float2bfloat16(v[1]); pk.u[1] = cv.s;
  cv.h = __float2bfloat16(v[2]); pk.u[2] = cv.s;
  cv.h = __float2bfloat16(v[3]); pk.u[3] = cv.s;
  return pk.w;
}

// --- bucket histogram (bucket = dst >> 8) ---
__global__ __launch_bounds__(256) void k_bhist(const int* __restrict__ ei,
    int* __restrict__ ghist, int E, int NB) {
  __shared__ int h[NBMAX];
  int t = threadIdx.x;
  for (int i = t; i < NBMAX; i += 256) h[i] = 0;
  __syncthreads();
  int base = blockIdx.x * 4096;
  #pragma unroll
  for (int j = 0; j < 16; ++j) {
    int e = base + j * 256 + t;
    if (e < E) atomicAdd(&h[ei[E + e] >> 8], 1);
  }
  __syncthreads();
  for (int i = t; i < NB; i += 256)
    if (h[i]) atomicAdd(&ghist[i], h[i]);
}

// --- exclusive scan of bucket counts -> bbase, init gcursor ---
__global__ __launch_bounds__(NBMAX) void k_bscan(const int* __restrict__ ghist,
    int* __restrict__ bbase, int* __restrict__ gcursor, int NB, int E) {
  __shared__ int buf[NBMAX];
  int t = threadIdx.x;
  int v = (t < NB) ? ghist[t] : 0;
  buf[t] = v;
  __syncthreads();
  for (int d = 1; d < NBMAX; d <<= 1) {
    int w = (t >= d) ? buf[t - d] : 0;
    __syncthreads();
    buf[t] += w;
    __syncthreads();
  }
  if (t < NB) {
    int ex = buf[t] - v;
    bbase[t] = ex;
    gcursor[t] = ex;
  }
  if (t == 0) bbase[NB] = E;
}

// --- partition edges into buckets with coalesced writes ---
__global__ __launch_bounds__(512) void k_part(const int* __restrict__ ei,
    const int* __restrict__ ea, int* __restrict__ gcursor,
    unsigned* __restrict__ ebuf, int E, int NB) {
  __shared__ unsigned reorder[PCHUNK];
  __shared__ unsigned short bkt[PCHUNK];
  __shared__ int hist[NBMAX], startl[NBMAX], cursor[NBMAX], gb[NBMAX], scanb[NBMAX];
  int t = threadIdx.x;
  int base = blockIdx.x * PCHUNK;
  int cn = min(PCHUNK, E - base);
  unsigned key[16];
  short bb[16];
  hist[t] = 0;
  __syncthreads();
  #pragma unroll
  for (int j = 0; j < 16; ++j) {
    int e = base + j * 512 + t;
    bb[j] = -1;
    if (e < E) {
      int src = ei[e], dst = ei[E + e], rel = ea[e];
      key[j] = ((unsigned)(dst & (BNODES - 1)) << 20) | ((unsigned)src << 3) | (unsigned)rel;
      int b = dst >> 8;
      bb[j] = (short)b;
      atomicAdd(&hist[b], 1);
    }
  }
  __syncthreads();
  int v = hist[t];
  scanb[t] = v;
  __syncthreads();
  for (int d = 1; d < NBMAX; d <<= 1) {
    int w = (t >= d) ? scanb[t - d] : 0;
    __syncthreads();
    scanb[t] += w;
    __syncthreads();
  }
  startl[t] = scanb[t] - v;
  cursor[t] = scanb[t] - v;
  __syncthreads();
  #pragma unroll
  for (int j = 0; j < 16; ++j) {
    if (bb[j] >= 0) {
      int pos = atomicAdd(&cursor[bb[j]], 1);
      reorder[pos] = key[j];
      bkt[pos] = (unsigned short)bb[j];
    }
  }
  __syncthreads();
  if (t < NB && hist[t] > 0) gb[t] = atomicAdd(&gcursor[t], hist[t]);
  __syncthreads();
  for (int p = t; p < cn; p += 512) {
    int b = bkt[p];
    ebuf[gb[b] + (p - startl[b])] = reorder[p];
  }
}

// --- per-bucket counting sort by (dl,rel) with per-dst 8-aligned padding ---
__global__ __launch_bounds__(512) void k_sort(const int* __restrict__ bbase,
    const unsigned* __restrict__ ebuf, unsigned* __restrict__ ebuf2,
    float* __restrict__ wbuf, int* __restrict__ rps, int* __restrict__ rpc,
    int NB) {
  __shared__ int hist[2048];
  __shared__ float invw[2048];
  __shared__ int dlc[256];
  __shared__ unsigned sorted[SORTCAP];
  int t = threadIdx.x;
  int b = blockIdx.x;
  int s = bbase[b], e = bbase[b + 1];
  int out_s = ((s + 7) & ~7) + (b << 11);   // 8-aligned bucket base with pad slack
  for (int i = t; i < 2048; i += 512) hist[i] = 0;
  __syncthreads();
  for (int p = s + t; p < e; p += 512) {
    unsigned k = ebuf[p];
    atomicAdd(&hist[((k >> 20) << 3) | (k & 7u)], 1);
  }
  __syncthreads();
  for (int i = t; i < 2048; i += 512) {
    int c = hist[i];
    invw[i] = 1.0f / (float)(c > 1 ? c : 1);
  }
  __syncthreads();
  int pr[8];
  int cdl = 0, pc = 0;
  if (t < 256) {
    #pragma unroll
    for (int r = 0; r < 8; ++r) { pr[r] = cdl; cdl += hist[8 * t + r]; }
    pc = (cdl + 7) & ~7;
    dlc[t] = pc;
  }
  __syncthreads();
  for (int d = 1; d < 256; d <<= 1) {
    int w = (t < 256 && t >= d) ? dlc[t - d] : 0;
    __syncthreads();
    if (t < 256) dlc[t] += w;
    __syncthreads();
  }
  if (t < 256) {
    int ebase = dlc[t] - pc;
    #pragma unroll
    for (int r = 0; r < 8; ++r) hist[8 * t + r] = ebase + pr[r];
    rps[(b << 8) + t] = out_s + ebase;
    rpc[(b << 8) + t] = cdl;
  }
  __syncthreads();
  int ptot = dlc[255];
  if (ptot <= SORTCAP) {
    for (int p = t; p < ptot; p += 512) sorted[p] = 0xFFFFFFFFu;
    __syncthreads();
    for (int p = s + t; p < e; p += 512) {
      unsigned k = ebuf[p];
      int pos = atomicAdd(&hist[((k >> 20) << 3) | (k & 7u)], 1);
      sorted[pos] = k;
    }
    __syncthreads();
    for (int p = t; p < ptot; p += 512) {
      unsigned k = sorted[p];
      int o = out_s + p;
      if (k == 0xFFFFFFFFu) { ebuf2[o] = 0u; wbuf[o] = 0.f; }
      else { ebuf2[o] = k; wbuf[o] = invw[((k >> 20) << 3) | (k & 7u)]; }
    }
  } else {
    if (t < 256) {
      int ebase = dlc[t] - pc;
      for (int p = ebase + cdl; p < dlc[t]; ++p) {
        ebuf2[out_s + p] = 0u; wbuf[out_s + p] = 0.f;
      }
    }
    __syncthreads();
    for (int p = s + t; p < e; p += 512) {
      unsigned k = ebuf[p];
      int bin = ((k >> 20) << 3) | (k & 7u);
      int pos = atomicAdd(&hist[bin], 1);
      ebuf2[out_s + pos] = k;
      wbuf[out_s + pos] = invw[bin];
    }
  }
}

// --- build padded col-major bf16 weight panels ---
__global__ __launch_bounds__(256) void k_prepw(const float* __restrict__ W1,
    const float* __restrict__ root1, const float* __restrict__ W2,
    const float* __restrict__ root2, unsigned short* __restrict__ Wcat,
    unsigned short* __restrict__ W2cat) {
  int id = blockIdx.x * 256 + threadIdx.x;
  union { __hip_bfloat16 h; unsigned short u; } cv;
  if (id < W1ELTS) {
    int c = id / W1STR, kk = id - c * W1STR;
    float v = 0.f;
    if (kk < FIN)
      v = (c < 256) ? W1[((size_t)(c >> 5) * FIN + kk) * HH1 + (c & 31)]
                    : root1[(size_t)kk * HH1 + (c - 256)];
    cv.h = __float2bfloat16(v);
    Wcat[id] = cv.u;
  } else if (id < W1ELTS + W2ELTS) {
    int id2 = id - W1ELTS;
    int c = id2 / W2STR, kk = id2 - c * W2STR;
    float v = 0.f;
    if (kk < HH1)
      v = (c < 128) ? W2[((size_t)(c >> 4) * HH1 + kk) * HH2 + (c & 15)]
                    : root2[(size_t)kk * HH2 + (c - 128)];
    cv.h = __float2bfloat16(v);
    W2cat[id2] = cv.u;
  }
}

// --- MFMA gemm1, swapped operands (A=W, B=x), ONE CHUNK PER BLOCK.
// grid = nchunk (3125): 5 resident blocks/CU x 6 waves x 16 outstanding loads
// keeps the memory pipe full (load phases of different blocks interleave).
__global__ __launch_bounds__(384) void k_gemm1m(const float* __restrict__ x,
    const unsigned short* __restrict__ Wcat, const float* __restrict__ b1,
    __hip_bfloat16* __restrict__ xw, float* __restrict__ agg, int N, int nchunk) {
  int lane = threadIdx.x & 63;
  int wv = threadIdx.x >> 6;       // 0..5
  int g = lane >> 4, lc = lane & 15;
  int cj0 = wv * 3;
  bf16x8 Wf[3][4];
  #pragma unroll
  for (int j = 0; j < 3; ++j)
    #pragma unroll
    for (int ks = 0; ks < 4; ++ks)
      Wf[j][ks] = *(const bf16x8*)(Wcat + (size_t)((cj0 + j) * 16 + lc) * W1STR + ks * 32 + g * 8);

  for (int ch = blockIdx.x; ch < nchunk; ch += gridDim.x) {
    long base = (long)ch * 32;
    long r0 = base + lc;       if (r0 > N - 1) r0 = N - 1;
    long r1 = base + 16 + lc;  if (r1 > N - 1) r1 = N - 1;
    const float4* p0 = (const float4*)(x + r0 * FIN + g * 8);
    const float4* p1 = (const float4*)(x + r1 * FIN + g * 8);
    float4 raw[16];
    #pragma unroll
    for (int ks = 0; ks < 4; ++ks) {
      raw[2 * ks]     = p0[ks * 8];
      raw[2 * ks + 1] = p0[ks * 8 + 1];
    }
    #pragma unroll
    for (int ks = 0; ks < 4; ++ks) {
      raw[8 + 2 * ks]     = p1[ks * 8];
      raw[8 + 2 * ks + 1] = p1[ks * 8 + 1];
    }
    bf16x8 xf0[4], xf1[4];
    #pragma unroll
    for (int ks = 0; ks < 4; ++ks) {
      xf0[ks] = cvt8r(raw[2 * ks], raw[2 * ks + 1]);
      xf1[ks] = cvt8r(raw[8 + 2 * ks], raw[8 + 2 * ks + 1]);
    }
    f32x4 acc0[3], acc1[3];
    #pragma unroll
    for (int j = 0; j < 3; ++j) {
      acc0[j] = (f32x4){0.f, 0.f, 0.f, 0.f};
      acc1[j] = (f32x4){0.f, 0.f, 0.f, 0.f};
    }
    #pragma unroll
    for (int j = 0; j < 3; ++j)
      #pragma unroll
      for (int ks = 0; ks < 4; ++ks) {
        acc0[j] = __builtin_amdgcn_mfma_f32_16x16x32_bf16(Wf[j][ks], xf0[ks], acc0[j], 0, 0, 0);
        acc1[j] = __builtin_amdgcn_mfma_f32_16x16x32_bf16(Wf[j][ks], xf1[ks], acc1[j], 0, 0, 0);
      }
    long row0 = base + lc;
    if (row0 < N) {
      #pragma unroll
      for (int j = 0; j < 3; ++j) {
        int c0 = (cj0 + j) * 16 + 4 * g;
        if (c0 < 256) {
          *(uint2*)((unsigned short*)xw + row0 * 256 + c0) = pack4bf(acc0[j]);
        } else {
          float4 bb = *(const float4*)(b1 + (c0 - 256));
          float4 o = make_float4(acc0[j][0] + bb.x, acc0[j][1] + bb.y,
                                 acc0[j][2] + bb.z, acc0[j][3] + bb.w);
          *(float4*)(agg + row0 * HH1 + (c0 - 256)) = o;
        }
      }
    }
    long row1 = base + 16 + lc;
    if (row1 < N) {
      #pragma unroll
      for (int j = 0; j < 3; ++j) {
        int c0 = (cj0 + j) * 16 + 4 * g;
        if (c0 < 256) {
          *(uint2*)((unsigned short*)xw + row1 * 256 + c0) = pack4bf(acc1[j]);
        } else {
          float4 bb = *(const float4*)(b1 + (c0 - 256));
          float4 o = make_float4(acc1[j][0] + bb.x, acc1[j][1] + bb.y,
                                 acc1[j][2] + bb.z, acc1[j][3] + bb.w);
          *(float4*)(agg + row1 * HH1 + (c0 - 256)) = o;
        }
      }
    }
  }
}

// layer-1 aggregation: one wave64 per dst; 32 h-lanes x 2 edge-substreams
__global__ __launch_bounds__(256) void k_agg1(const int* __restrict__ rps,
    const int* __restrict__ rpc, const unsigned* __restrict__ eb,
    const float* __restrict__ wb, const __hip_bfloat16* __restrict__ xw,
    float* __restrict__ agg, int N) {
  int d = blockIdx.x * 4 + (threadIdx.x >> 6);
  if (d >= N) return;
  int lane = threadIdx.x & 63;
  int h = lane & 31, half = lane >> 5;
  int s = rps[d];
  int cnt = rpc[d];
  float acc = 0.f;
  for (int j = half * 8; j < cnt; j += 16) {
    const unsigned* kp = eb + s + j;
    uint4 ka = *(const uint4*)kp;
    uint4 kb = *(const uint4*)(kp + 4);
    float4 wa = *(const float4*)(wb + s + j);
    float4 wc = *(const float4*)(wb + s + j + 4);
    unsigned ks[8] = {ka.x, ka.y, ka.z, ka.w, kb.x, kb.y, kb.z, kb.w};
    float ws[8] = {wa.x, wa.y, wa.z, wa.w, wc.x, wc.y, wc.z, wc.w};
    #pragma unroll
    for (int u = 0; u < 8; ++u) {
      unsigned idx = ks[u] & 0xFFFFFu;
      float v = __bfloat162float(xw[((size_t)idx << 5) + h]);
      acc = fmaf(ws[u], v, acc);
    }
  }
  acc += __shfl_xor(acc, 32);
  if (half == 0) agg[((size_t)d << 5) + h] += acc;
}

// --- MFMA gemm2, swapped operands, LDS-staged weights + LDS-staged epilogue.
// 6 waves x 32 rows = 192 rows/block.
__global__ __launch_bounds__(384) void k_gemm2m(const float* __restrict__ agg1,
    const unsigned short* __restrict__ W2cat, const float* __restrict__ b2,
    __hip_bfloat16* __restrict__ xw, float* __restrict__ agg, int N) {
  __shared__ short WL[W2ELTS];      // 11520 B
  __shared__ short XT[192 * 132];   // 50688 B, stride 132 shorts = 264 B
  __shared__ float AG[192 * 20];    // 15360 B, stride 20 floats = 80 B
  int t = threadIdx.x;
  for (int i = t; i < W2ELTS / 8; i += 384)
    ((uint4*)WL)[i] = ((const uint4*)W2cat)[i];
  __syncthreads();
  int lane = t & 63;
  int wv = t >> 6;                  // 0..5
  int g = lane >> 4, lc = lane & 15;
  long nb = (long)blockIdx.x * 192 + wv * 32;
  f32x4 acc[2][9];
  #pragma unroll
  for (int m = 0; m < 2; ++m)
    #pragma unroll
    for (int j = 0; j < 9; ++j)
      acc[m][j] = (f32x4){0.f, 0.f, 0.f, 0.f};
  long rowA0 = nb + lc;       if (rowA0 > N - 1) rowA0 = N - 1;
  long rowA1 = nb + 16 + lc;  if (rowA1 > N - 1) rowA1 = N - 1;
  bf16x8 a0 = cvt8relu(agg1 + rowA0 * HH1 + g * 8);
  bf16x8 a1 = cvt8relu(agg1 + rowA1 * HH1 + g * 8);
  #pragma unroll
  for (int j = 0; j < 9; ++j) {
    bf16x8 bf = *(const bf16x8*)(WL + (16 * j + lc) * W2STR + g * 8);
    acc[0][j] = __builtin_amdgcn_mfma_f32_16x16x32_bf16(bf, a0, acc[0][j], 0, 0, 0);
    acc[1][j] = __builtin_amdgcn_mfma_f32_16x16x32_bf16(bf, a1, acc[1][j], 0, 0, 0);
  }
  #pragma unroll
  for (int m = 0; m < 2; ++m) {
    int lrow = wv * 32 + 16 * m + lc;
    #pragma unroll
    for (int j = 0; j < 8; ++j)
      *(uint2*)(XT + lrow * 132 + 16 * j + 4 * g) = pack4bf(acc[m][j]);
    float4 bb = *(const float4*)(b2 + 4 * g);
    *(float4*)(AG + lrow * 20 + 4 * g) =
        make_float4(acc[m][8][0] + bb.x, acc[m][8][1] + bb.y,
                    acc[m][8][2] + bb.z, acc[m][8][3] + bb.w);
  }
  __syncthreads();
  long base = (long)blockIdx.x * 192;
  for (int i = t; i < 6144; i += 384) {
    int row = i >> 5, u = i & 31;
    long grow = base + row;
    if (grow < N)
      *(uint2*)((unsigned short*)xw + grow * 128 + u * 4) = *(const uint2*)(XT + row * 132 + u * 4);
  }
  for (int i = t; i < 768; i += 384) {
    int row = i >> 2, q = i & 3;
    long grow = base + row;
    if (grow < N)
      *(float4*)(agg + grow * HH2 + q * 4) = *(const float4*)(AG + row * 20 + q * 4);
  }
}

// --- FUSED layer-2 aggregation + relu + graph max-pool.
__global__ __launch_bounds__(256) void k_agg2f(const int* __restrict__ rps,
    const int* __restrict__ rpc, const unsigned* __restrict__ eb,
    const float* __restrict__ wb, const __hip_bfloat16* __restrict__ xw,
    const float* __restrict__ agg2r, const int* __restrict__ batch,
    unsigned* __restrict__ pooled, int N) {
  int d = blockIdx.x * 4 + (threadIdx.x >> 6);
  if (d >= N) return;
  int lane = threadIdx.x & 63;
  int h = lane & 15, q = lane >> 4;
  int s = rps[d];
  int cnt = rpc[d];
  float acc = 0.f;
  for (int j = q * 8; j < cnt; j += 32) {
    const unsigned* kp = eb + s + j;
    uint4 ka = *(const uint4*)kp;
    uint4 kb = *(const uint4*)(kp + 4);
    float4 wa = *(const float4*)(wb + s + j);
    float4 wc = *(const float4*)(wb + s + j + 4);
    unsigned ks[8] = {ka.x, ka.y, ka.z, ka.w, kb.x, kb.y, kb.z, kb.w};
    float ws[8] = {wa.x, wa.y, wa.z, wa.w, wc.x, wc.y, wc.z, wc.w};
    #pragma unroll
    for (int u = 0; u < 8; ++u) {
      unsigned idx = ks[u] & 0xFFFFFu;
      float v = __bfloat162float(xw[((size_t)idx << 4) + h]);
      acc = fmaf(ws[u], v, acc);
    }
  }
  acc += __shfl_xor(acc, 32);
  acc += __shfl_xor(acc, 16);
  if (q == 0) {
    float v = fmaxf(acc + agg2r[((size_t)d << 4) + h], 0.f);
    atomicMax(&pooled[batch[d] * HH2 + h], __float_as_uint(v));
  }
}

__global__ __launch_bounds__(256) void k_dense(const float* __restrict__ pooled,
    const float* __restrict__ dw, const float* __restrict__ db,
    float* __restrict__ out, int Gn) {
  int g = blockIdx.x * 256 + threadIdx.x;
  if (g < Gn) {
    float s = db[0];
    #pragma unroll
    for (int h = 0; h < HH2; ++h) s += pooled[(size_t)g * HH2 + h] * dw[h];
    out[g] = s;
  }
}

extern "C" void kernel_launch(void* const* d_in, const int* in_sizes, int n_in,
                              void* d_out, int out_size, void* d_ws, size_t ws_size,
                              hipStream_t stream) {
  const float* x     = (const float*)d_in[0];
  const int*   ei    = (const int*)d_in[1];
  const int*   ea    = (const int*)d_in[2];
  const int*   batch = (const int*)d_in[3];
  const float* W1    = (const float*)d_in[4];
  const float* root1 = (const float*)d_in[5];
  const float* b1    = (const float*)d_in[6];
  const float* W2    = (const float*)d_in[7];
  const float* root2 = (const float*)d_in[8];
  const float* b2    = (const float*)d_in[9];
  const float* dw    = (const float*)d_in[10];
  const float* db    = (const float*)d_in[11];
  float* out = (float*)d_out;

  const int N  = in_sizes[0] / FIN;
  const int E  = in_sizes[2];
  const int Gn = out_size;
  const int NB = (N + BNODES - 1) / BNODES;   // 391 for N=100000

  char* ws = (char*)d_ws;
  size_t off = 0;
  auto walloc = [&](size_t bytes) -> void* {
    void* p = (void*)(ws + off);
    off += (bytes + 255) & ~(size_t)255;
    return p;
  };
  const size_t EP = (size_t)E + (size_t)NBMAX * 2048 + 64;  // padded edge capacity
  int*            ghist   = (int*)            walloc((size_t)NBMAX * 4);
  int*            bbase   = (int*)            walloc(((size_t)NBMAX + 1) * 4);
  int*            gcursor = (int*)            walloc((size_t)NBMAX * 4);
  unsigned*       ebuf    = (unsigned*)       walloc((size_t)E * 4);
  unsigned*       ebuf2   = (unsigned*)       walloc(EP * 4);
  float*          wbuf    = (float*)          walloc(EP * 4);
  int*            rps     = (int*)            walloc((size_t)NBMAX * 256 * 4);
  int*            rpc     = (int*)            walloc((size_t)NBMAX * 256 * 4);
  unsigned short* Wcat    = (unsigned short*) walloc((size_t)W1ELTS * 2);
  unsigned short* W2cat   = (unsigned short*) walloc((size_t)W2ELTS * 2);
  __hip_bfloat16* xw1     = (__hip_bfloat16*) walloc((size_t)N * RNUM * HH1 * 2);
  float*          agg1    = (float*)          walloc((size_t)N * HH1 * 4);
  __hip_bfloat16* xw2     = (__hip_bfloat16*) walloc((size_t)N * RNUM * HH2 * 2);
  float*          agg2r   = (float*)          walloc((size_t)N * HH2 * 4);
  unsigned*       pooled  = (unsigned*)       walloc((size_t)Gn * HH2 * 4);

  hipMemsetAsync(ghist, 0, (size_t)NBMAX * 4, stream);
  hipMemsetAsync(pooled, 0, (size_t)Gn * HH2 * 4, stream);

  k_prepw<<<(W1ELTS + W2ELTS + 255) / 256, 256, 0, stream>>>(W1, root1, W2, root2, Wcat, W2cat);
  k_bhist<<<(E + 4095) / 4096, 256, 0, stream>>>(ei, ghist, E, NB);
  k_bscan<<<1, NBMAX, 0, stream>>>(ghist, bbase, gcursor, NB, E);
  k_part<<<(E + PCHUNK - 1) / PCHUNK, 512, 0, stream>>>(ei, ea, gcursor, ebuf, E, NB);
  k_sort<<<NB, 512, 0, stream>>>(bbase, ebuf, ebuf2, wbuf, rps, rpc, NB);

  {
    int nchunk = (N + 31) / 32;
    k_gemm1m<<<nchunk, 384, 0, stream>>>(x, Wcat, b1, xw1, agg1, N, nchunk);
  }
  k_agg1<<<(N + 3) / 4, 256, 0, stream>>>(rps, rpc, ebuf2, wbuf, xw1, agg1, N);
  k_gemm2m<<<(N + 191) / 192, 384, 0, stream>>>(agg1, W2cat, b2, xw2, agg2r, N);
  k_agg2f<<<(N + 3) / 4, 256, 0, stream>>>(rps, rpc, ebuf2, wbuf, xw2,
                                           agg2r, batch, pooled, N);
  k_dense<<<(Gn + 255) / 256, 256, 0, stream>>>((const float*)pooled, dw, db, out, Gn);
}

// Round 17
// 263.215 us; speedup vs baseline: 1.0496x; 1.0496x over previous
//
#include <hip/hip_runtime.h>
#include <hip/hip_bf16.h>

#define RNUM 8
#define HH1 32
#define HH2 16
#define FIN 128
#define BNODES 256      // nodes per bucket
#define NBMAX 512
#define PCHUNK 8192     // edges per partition block
#define SORTCAP 11264   // max PADDED edges per bucket the LDS sort handles
#define GEMMB 512       // gemm sub-grid blocks in fused kernel (r15-proven)

#define W1STR 136       // padded col stride (shorts) for Wcat  [288][136]
#define W1ELTS (288 * W1STR)
#define W2STR 40        // padded col stride (shorts) for W2cat [144][40]
#define W2ELTS (144 * W2STR)

typedef short bf16x8 __attribute__((ext_vector_type(8)));
typedef float f32x4 __attribute__((ext_vector_type(4)));

__device__ inline bf16x8 cvt8r(float4 a, float4 b) {
  float tmp[8] = {a.x, a.y, a.z, a.w, b.x, b.y, b.z, b.w};
  bf16x8 r;
  #pragma unroll
  for (int j = 0; j < 8; ++j) {
    union { __hip_bfloat16 h; short s; } cv;
    cv.h = __float2bfloat16(tmp[j]);
    r[j] = cv.s;
  }
  return r;
}

__device__ inline bf16x8 cvt8relu(const float* __restrict__ p) {
  float tmp[8];
  *(float4*)tmp = *(const float4*)p;
  *(float4*)(tmp + 4) = *(const float4*)(p + 4);
  bf16x8 r;
  #pragma unroll
  for (int j = 0; j < 8; ++j) {
    union { __hip_bfloat16 h; short s; } cv;
    cv.h = __float2bfloat16(fmaxf(tmp[j], 0.f));
    r[j] = cv.s;
  }
  return r;
}

__device__ inline uint2 pack4bf(f32x4 v) {
  union { unsigned short u[4]; uint2 w; } pk;
  union { __hip_bfloat16 h; unsigned short s; } cv;
  cv.h = __float2bfloat16(v[0]); pk.u[0] = cv.s;
  cv.h = __float2bfloat16(v[1]); pk.u[1] = cv.s;
  cv.h = __float2bfloat16(v[2]); pk.u[2] = cv.s;
  cv.h = __float2bfloat16(v[3]); pk.u[3] = cv.s;
  return pk.w;
}

// --- bucket histogram (bucket = dst >> 8) ---
__global__ __launch_bounds__(256) void k_bhist(const int* __restrict__ ei,
    int* __restrict__ ghist, int E, int NB) {
  __shared__ int h[NBMAX];
  int t = threadIdx.x;
  for (int i = t; i < NBMAX; i += 256) h[i] = 0;
  __syncthreads();
  int base = blockIdx.x * 4096;
  #pragma unroll
  for (int j = 0; j < 16; ++j) {
    int e = base + j * 256 + t;
    if (e < E) atomicAdd(&h[ei[E + e] >> 8], 1);
  }
  __syncthreads();
  for (int i = t; i < NB; i += 256)
    if (h[i]) atomicAdd(&ghist[i], h[i]);
}

// --- exclusive scan of bucket counts -> bbase, init gcursor ---
__global__ __launch_bounds__(NBMAX) void k_bscan(const int* __restrict__ ghist,
    int* __restrict__ bbase, int* __restrict__ gcursor, int NB, int E) {
  __shared__ int buf[NBMAX];
  int t = threadIdx.x;
  int v = (t < NB) ? ghist[t] : 0;
  buf[t] = v;
  __syncthreads();
  for (int d = 1; d < NBMAX; d <<= 1) {
    int w = (t >= d) ? buf[t - d] : 0;
    __syncthreads();
    buf[t] += w;
    __syncthreads();
  }
  if (t < NB) {
    int ex = buf[t] - v;
    bbase[t] = ex;
    gcursor[t] = ex;
  }
  if (t == 0) bbase[NB] = E;
}

// --- FUSED: blocks [0,NPART) partition edges; blocks [NPART,NPART+GEMMB) do
// MFMA gemm1 (independent data; overlaps BW-bound part with latency-bound gemm).
__global__ __launch_bounds__(512) void k_fuse1(
    const int* __restrict__ ei, const int* __restrict__ ea,
    int* __restrict__ gcursor, unsigned* __restrict__ ebuf,
    const float* __restrict__ x, const unsigned short* __restrict__ Wcat,
    const float* __restrict__ b1, __hip_bfloat16* __restrict__ xw,
    float* __restrict__ agg, int E, int NB, int N, int nchunk, int NPART) {
  __shared__ unsigned reorder[PCHUNK];
  __shared__ unsigned short bkt[PCHUNK];
  __shared__ int hist[NBMAX], startl[NBMAX], cursor[NBMAX], gb[NBMAX], scanb[NBMAX];
  int t = threadIdx.x;

  if (blockIdx.x < NPART) {
    // ---------------- partition path (512 threads) ----------------
    int base = blockIdx.x * PCHUNK;
    int cn = min(PCHUNK, E - base);
    unsigned key[16];
    short bb[16];
    hist[t] = 0;
    __syncthreads();
    #pragma unroll
    for (int j = 0; j < 16; ++j) {
      int e = base + j * 512 + t;
      bb[j] = -1;
      if (e < E) {
        int src = ei[e], dst = ei[E + e], rel = ea[e];
        key[j] = ((unsigned)(dst & (BNODES - 1)) << 20) | ((unsigned)src << 3) | (unsigned)rel;
        int b = dst >> 8;
        bb[j] = (short)b;
        atomicAdd(&hist[b], 1);
      }
    }
    __syncthreads();
    int v = hist[t];
    scanb[t] = v;
    __syncthreads();
    for (int d = 1; d < NBMAX; d <<= 1) {
      int w = (t >= d) ? scanb[t - d] : 0;
      __syncthreads();
      scanb[t] += w;
      __syncthreads();
    }
    startl[t] = scanb[t] - v;
    cursor[t] = scanb[t] - v;
    __syncthreads();
    #pragma unroll
    for (int j = 0; j < 16; ++j) {
      if (bb[j] >= 0) {
        int pos = atomicAdd(&cursor[bb[j]], 1);
        reorder[pos] = key[j];
        bkt[pos] = (unsigned short)bb[j];
      }
    }
    __syncthreads();
    if (t < NB && hist[t] > 0) gb[t] = atomicAdd(&gcursor[t], hist[t]);
    __syncthreads();
    for (int p = t; p < cn; p += 512) {
      int b = bkt[p];
      ebuf[gb[b] + (p - startl[b])] = reorder[p];
    }
    return;
  }

  // ---------------- gemm path (waves 0..5 of 8) ----------------
  if (t >= 384) return;
  int lane = t & 63;
  int wv = t >> 6;                 // 0..5
  int g = lane >> 4, lc = lane & 15;
  int cj0 = wv * 3;
  bf16x8 Wf[3][4];
  #pragma unroll
  for (int j = 0; j < 3; ++j)
    #pragma unroll
    for (int ks = 0; ks < 4; ++ks)
      Wf[j][ks] = *(const bf16x8*)(Wcat + (size_t)((cj0 + j) * 16 + lc) * W1STR + ks * 32 + g * 8);

  int gstride = gridDim.x - NPART;
  for (int ch = blockIdx.x - NPART; ch < nchunk; ch += gstride) {
    long base = (long)ch * 32;
    long r0 = base + lc;       if (r0 > N - 1) r0 = N - 1;
    long r1 = base + 16 + lc;  if (r1 > N - 1) r1 = N - 1;
    const float4* p0 = (const float4*)(x + r0 * FIN + g * 8);
    const float4* p1 = (const float4*)(x + r1 * FIN + g * 8);
    float4 raw[16];
    #pragma unroll
    for (int ks = 0; ks < 4; ++ks) {
      raw[2 * ks]     = p0[ks * 8];
      raw[2 * ks + 1] = p0[ks * 8 + 1];
    }
    #pragma unroll
    for (int ks = 0; ks < 4; ++ks) {
      raw[8 + 2 * ks]     = p1[ks * 8];
      raw[8 + 2 * ks + 1] = p1[ks * 8 + 1];
    }
    bf16x8 xf0[4], xf1[4];
    #pragma unroll
    for (int ks = 0; ks < 4; ++ks) {
      xf0[ks] = cvt8r(raw[2 * ks], raw[2 * ks + 1]);
      xf1[ks] = cvt8r(raw[8 + 2 * ks], raw[8 + 2 * ks + 1]);
    }
    f32x4 acc0[3], acc1[3];
    #pragma unroll
    for (int j = 0; j < 3; ++j) {
      acc0[j] = (f32x4){0.f, 0.f, 0.f, 0.f};
      acc1[j] = (f32x4){0.f, 0.f, 0.f, 0.f};
    }
    #pragma unroll
    for (int j = 0; j < 3; ++j)
      #pragma unroll
      for (int ks = 0; ks < 4; ++ks) {
        acc0[j] = __builtin_amdgcn_mfma_f32_16x16x32_bf16(Wf[j][ks], xf0[ks], acc0[j], 0, 0, 0);
        acc1[j] = __builtin_amdgcn_mfma_f32_16x16x32_bf16(Wf[j][ks], xf1[ks], acc1[j], 0, 0, 0);
      }
    long row0 = base + lc;
    if (row0 < N) {
      #pragma unroll
      for (int j = 0; j < 3; ++j) {
        int c0 = (cj0 + j) * 16 + 4 * g;
        if (c0 < 256) {
          *(uint2*)((unsigned short*)xw + row0 * 256 + c0) = pack4bf(acc0[j]);
        } else {
          float4 bb = *(const float4*)(b1 + (c0 - 256));
          float4 o = make_float4(acc0[j][0] + bb.x, acc0[j][1] + bb.y,
                                 acc0[j][2] + bb.z, acc0[j][3] + bb.w);
          *(float4*)(agg + row0 * HH1 + (c0 - 256)) = o;
        }
      }
    }
    long row1 = base + 16 + lc;
    if (row1 < N) {
      #pragma unroll
      for (int j = 0; j < 3; ++j) {
        int c0 = (cj0 + j) * 16 + 4 * g;
        if (c0 < 256) {
          *(uint2*)((unsigned short*)xw + row1 * 256 + c0) = pack4bf(acc1[j]);
        } else {
          float4 bb = *(const float4*)(b1 + (c0 - 256));
          float4 o = make_float4(acc1[j][0] + bb.x, acc1[j][1] + bb.y,
                                 acc1[j][2] + bb.z, acc1[j][3] + bb.w);
          *(float4*)(agg + row1 * HH1 + (c0 - 256)) = o;
        }
      }
    }
  }
}

// --- per-bucket counting sort by (dl,rel) with per-dst 8-aligned padding ---
__global__ __launch_bounds__(512) void k_sort(const int* __restrict__ bbase,
    const unsigned* __restrict__ ebuf, unsigned* __restrict__ ebuf2,
    float* __restrict__ wbuf, int* __restrict__ rps, int* __restrict__ rpc,
    int NB) {
  __shared__ int hist[2048];
  __shared__ float invw[2048];
  __shared__ int dlc[256];
  __shared__ unsigned sorted[SORTCAP];
  int t = threadIdx.x;
  int b = blockIdx.x;
  int s = bbase[b], e = bbase[b + 1];
  int out_s = ((s + 7) & ~7) + (b << 11);   // 8-aligned bucket base with pad slack
  for (int i = t; i < 2048; i += 512) hist[i] = 0;
  __syncthreads();
  for (int p = s + t; p < e; p += 512) {
    unsigned k = ebuf[p];
    atomicAdd(&hist[((k >> 20) << 3) | (k & 7u)], 1);
  }
  __syncthreads();
  for (int i = t; i < 2048; i += 512) {
    int c = hist[i];
    invw[i] = 1.0f / (float)(c > 1 ? c : 1);
  }
  __syncthreads();
  int pr[8];
  int cdl = 0, pc = 0;
  if (t < 256) {
    #pragma unroll
    for (int r = 0; r < 8; ++r) { pr[r] = cdl; cdl += hist[8 * t + r]; }
    pc = (cdl + 7) & ~7;
    dlc[t] = pc;
  }
  __syncthreads();
  for (int d = 1; d < 256; d <<= 1) {
    int w = (t < 256 && t >= d) ? dlc[t - d] : 0;
    __syncthreads();
    if (t < 256) dlc[t] += w;
    __syncthreads();
  }
  if (t < 256) {
    int ebase = dlc[t] - pc;
    #pragma unroll
    for (int r = 0; r < 8; ++r) hist[8 * t + r] = ebase + pr[r];
    rps[(b << 8) + t] = out_s + ebase;
    rpc[(b << 8) + t] = cdl;
  }
  __syncthreads();
  int ptot = dlc[255];
  if (ptot <= SORTCAP) {
    for (int p = t; p < ptot; p += 512) sorted[p] = 0xFFFFFFFFu;
    __syncthreads();
    for (int p = s + t; p < e; p += 512) {
      unsigned k = ebuf[p];
      int pos = atomicAdd(&hist[((k >> 20) << 3) | (k & 7u)], 1);
      sorted[pos] = k;
    }
    __syncthreads();
    for (int p = t; p < ptot; p += 512) {
      unsigned k = sorted[p];
      int o = out_s + p;
      if (k == 0xFFFFFFFFu) { ebuf2[o] = 0u; wbuf[o] = 0.f; }
      else { ebuf2[o] = k; wbuf[o] = invw[((k >> 20) << 3) | (k & 7u)]; }
    }
  } else {
    if (t < 256) {
      int ebase = dlc[t] - pc;
      for (int p = ebase + cdl; p < dlc[t]; ++p) {
        ebuf2[out_s + p] = 0u; wbuf[out_s + p] = 0.f;
      }
    }
    __syncthreads();
    for (int p = s + t; p < e; p += 512) {
      unsigned k = ebuf[p];
      int bin = ((k >> 20) << 3) | (k & 7u);
      int pos = atomicAdd(&hist[bin], 1);
      ebuf2[out_s + pos] = k;
      wbuf[out_s + pos] = invw[bin];
    }
  }
}

// --- build padded col-major bf16 weight panels ---
__global__ __launch_bounds__(256) void k_prepw(const float* __restrict__ W1,
    const float* __restrict__ root1, const float* __restrict__ W2,
    const float* __restrict__ root2, unsigned short* __restrict__ Wcat,
    unsigned short* __restrict__ W2cat) {
  int id = blockIdx.x * 256 + threadIdx.x;
  union { __hip_bfloat16 h; unsigned short u; } cv;
  if (id < W1ELTS) {
    int c = id / W1STR, kk = id - c * W1STR;
    float v = 0.f;
    if (kk < FIN)
      v = (c < 256) ? W1[((size_t)(c >> 5) * FIN + kk) * HH1 + (c & 31)]
                    : root1[(size_t)kk * HH1 + (c - 256)];
    cv.h = __float2bfloat16(v);
    Wcat[id] = cv.u;
  } else if (id < W1ELTS + W2ELTS) {
    int id2 = id - W1ELTS;
    int c = id2 / W2STR, kk = id2 - c * W2STR;
    float v = 0.f;
    if (kk < HH1)
      v = (c < 128) ? W2[((size_t)(c >> 4) * HH1 + kk) * HH2 + (c & 15)]
                    : root2[(size_t)kk * HH2 + (c - 128)];
    cv.h = __float2bfloat16(v);
    W2cat[id2] = cv.u;
  }
}

// layer-1 aggregation: one wave64 per dst; 32 h-lanes x 2 edge-substreams
__global__ __launch_bounds__(256) void k_agg1(const int* __restrict__ rps,
    const int* __restrict__ rpc, const unsigned* __restrict__ eb,
    const float* __restrict__ wb, const __hip_bfloat16* __restrict__ xw,
    float* __restrict__ agg, int N) {
  int d = blockIdx.x * 4 + (threadIdx.x >> 6);
  if (d >= N) return;
  int lane = threadIdx.x & 63;
  int h = lane & 31, half = lane >> 5;
  int s = rps[d];
  int cnt = rpc[d];
  float acc = 0.f;
  for (int j = half * 8; j < cnt; j += 16) {
    const unsigned* kp = eb + s + j;
    uint4 ka = *(const uint4*)kp;
    uint4 kb = *(const uint4*)(kp + 4);
    float4 wa = *(const float4*)(wb + s + j);
    float4 wc = *(const float4*)(wb + s + j + 4);
    unsigned ks[8] = {ka.x, ka.y, ka.z, ka.w, kb.x, kb.y, kb.z, kb.w};
    float ws[8] = {wa.x, wa.y, wa.z, wa.w, wc.x, wc.y, wc.z, wc.w};
    #pragma unroll
    for (int u = 0; u < 8; ++u) {
      unsigned idx = ks[u] & 0xFFFFFu;
      float v = __bfloat162float(xw[((size_t)idx << 5) + h]);
      acc = fmaf(ws[u], v, acc);
    }
  }
  acc += __shfl_xor(acc, 32);
  if (half == 0) agg[((size_t)d << 5) + h] += acc;
}

// --- MFMA gemm2, swapped operands, LDS-staged weights + LDS-staged epilogue.
__global__ __launch_bounds__(384) void k_gemm2m(const float* __restrict__ agg1,
    const unsigned short* __restrict__ W2cat, const float* __restrict__ b2,
    __hip_bfloat16* __restrict__ xw, float* __restrict__ agg, int N) {
  __shared__ short WL[W2ELTS];      // 11520 B
  __shared__ short XT[192 * 132];   // 50688 B
  __shared__ float AG[192 * 20];    // 15360 B
  int t = threadIdx.x;
  for (int i = t; i < W2ELTS / 8; i += 384)
    ((uint4*)WL)[i] = ((const uint4*)W2cat)[i];
  __syncthreads();
  int lane = t & 63;
  int wv = t >> 6;                  // 0..5
  int g = lane >> 4, lc = lane & 15;
  long nb = (long)blockIdx.x * 192 + wv * 32;
  f32x4 acc[2][9];
  #pragma unroll
  for (int m = 0; m < 2; ++m)
    #pragma unroll
    for (int j = 0; j < 9; ++j)
      acc[m][j] = (f32x4){0.f, 0.f, 0.f, 0.f};
  long rowA0 = nb + lc;       if (rowA0 > N - 1) rowA0 = N - 1;
  long rowA1 = nb + 16 + lc;  if (rowA1 > N - 1) rowA1 = N - 1;
  bf16x8 a0 = cvt8relu(agg1 + rowA0 * HH1 + g * 8);
  bf16x8 a1 = cvt8relu(agg1 + rowA1 * HH1 + g * 8);
  #pragma unroll
  for (int j = 0; j < 9; ++j) {
    bf16x8 bf = *(const bf16x8*)(WL + (16 * j + lc) * W2STR + g * 8);
    acc[0][j] = __builtin_amdgcn_mfma_f32_16x16x32_bf16(bf, a0, acc[0][j], 0, 0, 0);
    acc[1][j] = __builtin_amdgcn_mfma_f32_16x16x32_bf16(bf, a1, acc[1][j], 0, 0, 0);
  }
  #pragma unroll
  for (int m = 0; m < 2; ++m) {
    int lrow = wv * 32 + 16 * m + lc;
    #pragma unroll
    for (int j = 0; j < 8; ++j)
      *(uint2*)(XT + lrow * 132 + 16 * j + 4 * g) = pack4bf(acc[m][j]);
    float4 bb = *(const float4*)(b2 + 4 * g);
    *(float4*)(AG + lrow * 20 + 4 * g) =
        make_float4(acc[m][8][0] + bb.x, acc[m][8][1] + bb.y,
                    acc[m][8][2] + bb.z, acc[m][8][3] + bb.w);
  }
  __syncthreads();
  long base = (long)blockIdx.x * 192;
  for (int i = t; i < 6144; i += 384) {
    int row = i >> 5, u = i & 31;
    long grow = base + row;
    if (grow < N)
      *(uint2*)((unsigned short*)xw + grow * 128 + u * 4) = *(const uint2*)(XT + row * 132 + u * 4);
  }
  for (int i = t; i < 768; i += 384) {
    int row = i >> 2, q = i & 3;
    long grow = base + row;
    if (grow < N)
      *(float4*)(agg + grow * HH2 + q * 4) = *(const float4*)(AG + row * 20 + q * 4);
  }
}

// --- FUSED layer-2 aggregation + relu + graph max-pool.
__global__ __launch_bounds__(256) void k_agg2f(const int* __restrict__ rps,
    const int* __restrict__ rpc, const unsigned* __restrict__ eb,
    const float* __restrict__ wb, const __hip_bfloat16* __restrict__ xw,
    const float* __restrict__ agg2r, const int* __restrict__ batch,
    unsigned* __restrict__ pooled, int N) {
  int d = blockIdx.x * 4 + (threadIdx.x >> 6);
  if (d >= N) return;
  int lane = threadIdx.x & 63;
  int h = lane & 15, q = lane >> 4;
  int s = rps[d];
  int cnt = rpc[d];
  float acc = 0.f;
  for (int j = q * 8; j < cnt; j += 32) {
    const unsigned* kp = eb + s + j;
    uint4 ka = *(const uint4*)kp;
    uint4 kb = *(const uint4*)(kp + 4);
    float4 wa = *(const float4*)(wb + s + j);
    float4 wc = *(const float4*)(wb + s + j + 4);
    unsigned ks[8] = {ka.x, ka.y, ka.z, ka.w, kb.x, kb.y, kb.z, kb.w};
    float ws[8] = {wa.x, wa.y, wa.z, wa.w, wc.x, wc.y, wc.z, wc.w};
    #pragma unroll
    for (int u = 0; u < 8; ++u) {
      unsigned idx = ks[u] & 0xFFFFFu;
      float v = __bfloat162float(xw[((size_t)idx << 4) + h]);
      acc = fmaf(ws[u], v, acc);
    }
  }
  acc += __shfl_xor(acc, 32);
  acc += __shfl_xor(acc, 16);
  if (q == 0) {
    float v = fmaxf(acc + agg2r[((size_t)d << 4) + h], 0.f);
    atomicMax(&pooled[batch[d] * HH2 + h], __float_as_uint(v));
  }
}

__global__ __launch_bounds__(256) void k_dense(const float* __restrict__ pooled,
    const float* __restrict__ dw, const float* __restrict__ db,
    float* __restrict__ out, int Gn) {
  int g = blockIdx.x * 256 + threadIdx.x;
  if (g < Gn) {
    float s = db[0];
    #pragma unroll
    for (int h = 0; h < HH2; ++h) s += pooled[(size_t)g * HH2 + h] * dw[h];
    out[g] = s;
  }
}

extern "C" void kernel_launch(void* const* d_in, const int* in_sizes, int n_in,
                              void* d_out, int out_size, void* d_ws, size_t ws_size,
                              hipStream_t stream) {
  const float* x     = (const float*)d_in[0];
  const int*   ei    = (const int*)d_in[1];
  const int*   ea    = (const int*)d_in[2];
  const int*   batch = (const int*)d_in[3];
  const float* W1    = (const float*)d_in[4];
  const float* root1 = (const float*)d_in[5];
  const float* b1    = (const float*)d_in[6];
  const float* W2    = (const float*)d_in[7];
  const float* root2 = (const float*)d_in[8];
  const float* b2    = (const float*)d_in[9];
  const float* dw    = (const float*)d_in[10];
  const float* db    = (const float*)d_in[11];
  float* out = (float*)d_out;

  const int N  = in_sizes[0] / FIN;
  const int E  = in_sizes[2];
  const int Gn = out_size;
  const int NB = (N + BNODES - 1) / BNODES;   // 391 for N=100000

  char* ws = (char*)d_ws;
  size_t off = 0;
  auto walloc = [&](size_t bytes) -> void* {
    void* p = (void*)(ws + off);
    off += (bytes + 255) & ~(size_t)255;
    return p;
  };
  const size_t EP = (size_t)E + (size_t)NBMAX * 2048 + 64;  // padded edge capacity
  int*            ghist   = (int*)            walloc((size_t)NBMAX * 4);
  int*            bbase   = (int*)            walloc(((size_t)NBMAX + 1) * 4);
  int*            gcursor = (int*)            walloc((size_t)NBMAX * 4);
  unsigned*       ebuf    = (unsigned*)       walloc((size_t)E * 4);
  unsigned*       ebuf2   = (unsigned*)       walloc(EP * 4);
  float*          wbuf    = (float*)          walloc(EP * 4);
  int*            rps     = (int*)            walloc((size_t)NBMAX * 256 * 4);
  int*            rpc     = (int*)            walloc((size_t)NBMAX * 256 * 4);
  unsigned short* Wcat    = (unsigned short*) walloc((size_t)W1ELTS * 2);
  unsigned short* W2cat   = (unsigned short*) walloc((size_t)W2ELTS * 2);
  __hip_bfloat16* xw1     = (__hip_bfloat16*) walloc((size_t)N * RNUM * HH1 * 2);
  float*          agg1    = (float*)          walloc((size_t)N * HH1 * 4);
  __hip_bfloat16* xw2     = (__hip_bfloat16*) walloc((size_t)N * RNUM * HH2 * 2);
  float*          agg2r   = (float*)          walloc((size_t)N * HH2 * 4);
  unsigned*       pooled  = (unsigned*)       walloc((size_t)Gn * HH2 * 4);

  hipMemsetAsync(ghist, 0, (size_t)NBMAX * 4, stream);
  hipMemsetAsync(pooled, 0, (size_t)Gn * HH2 * 4, stream);

  k_prepw<<<(W1ELTS + W2ELTS + 255) / 256, 256, 0, stream>>>(W1, root1, W2, root2, Wcat, W2cat);
  k_bhist<<<(E + 4095) / 4096, 256, 0, stream>>>(ei, ghist, E, NB);
  k_bscan<<<1, NBMAX, 0, stream>>>(ghist, bbase, gcursor, NB, E);

  {
    int NPART = (E + PCHUNK - 1) / PCHUNK;    // 391
    int nchunk = (N + 31) / 32;               // 3125
    k_fuse1<<<NPART + GEMMB, 512, 0, stream>>>(ei, ea, gcursor, ebuf,
                                               x, Wcat, b1, xw1, agg1,
                                               E, NB, N, nchunk, NPART);
  }
  k_sort<<<NB, 512, 0, stream>>>(bbase, ebuf, ebuf2, wbuf, rps, rpc, NB);
  k_agg1<<<(N + 3) / 4, 256, 0, stream>>>(rps, rpc, ebuf2, wbuf, xw1, agg1, N);
  k_gemm2m<<<(N + 191) / 192, 384, 0, stream>>>(agg1, W2cat, b2, xw2, agg2r, N);
  k_agg2f<<<(N + 3) / 4, 256, 0, stream>>>(rps, rpc, ebuf2, wbuf, xw2,
                                           agg2r, batch, pooled, N);
  k_dense<<<(Gn + 255) / 256, 256, 0, stream>>>((const float*)pooled, dw, db, out, Gn);
}